// Round 5
// baseline (141.219 us; speedup 1.0000x reference)
//
#include <hip/hip_runtime.h>
#include <math.h>

#define BB 2
#define CC 192
#define DI 384
#define SS 16
#define RR 12
#define KK 4

// ---------------- K1: one pass over x, all three axis-mean reductions ----------------
// grid = B*C, block = 1024. seq layout: seq[i][b][pos][c]
__global__ void k_reduce(const float* __restrict__ x, float* __restrict__ seq) {
  int bc = blockIdx.x; int b = bc / CC, c = bc % CC;
  const float* base = x + (size_t)bc * 32768;
  int t = threadIdx.x;
  int w = t & 31, r = t >> 5;
  float acc = 0.f;
  __shared__ float sH[32];
  __shared__ float sMat[1024];
  if (t < 32) sH[t] = 0.f;
  __syncthreads();
  for (int h = 0; h < 32; ++h) {
    float v = base[r * 1024 + h * 32 + w];
    acc += v;
    float vv = v;
    #pragma unroll
    for (int off = 32; off > 0; off >>= 1) vv += __shfl_down(vv, off, 64);
    if ((t & 63) == 0) atomicAdd(&sH[h], vv);
  }
  sMat[t] = acc;
  float s0 = acc;
  #pragma unroll
  for (int off = 16; off > 0; off >>= 1) s0 += __shfl_down(s0, off, 32);
  if (w == 0) seq[((0 * BB + b) * 32 + r) * CC + c] = s0 * (1.f / 1024.f);
  __syncthreads();
  if (t < 32) {
    float s2 = 0.f;
    for (int rr = 0; rr < 32; ++rr) s2 += sMat[rr * 32 + t];
    seq[((2 * BB + b) * 32 + t) * CC + c] = s2 * (1.f / 1024.f);
    seq[((1 * BB + b) * 32 + t) * CC + c] = sH[t] * (1.f / 1024.f);
  }
}

// ---------------- K2: LN + in-proj(4 tokens xm + own z) + conv+silu + xp + dt, per token ----------------
// grid = 192, block = 384
__global__ void k_convall(const float* __restrict__ seq, const float* __restrict__ ln_w,
                          const float* __restrict__ ln_b, const float* __restrict__ in_w,
                          const float* __restrict__ conv_w, const float* __restrict__ conv_b,
                          const float* __restrict__ xp_w, const float* __restrict__ dt_w,
                          const float* __restrict__ dt_b, float* __restrict__ xc,
                          float* __restrict__ zbuf, float* __restrict__ dbc,
                          float* __restrict__ dtout) {
  int tok = blockIdx.x; int l = tok & 31; int tb = tok >> 5; int i = tb / BB;
  int t = threadIdx.x;
  __shared__ float sseq[4][CC];
  __shared__ float smu[4], sri[4];
  __shared__ float sxm[4][DI];
  __shared__ float xcl[DI];
  __shared__ float dbcl[44];
  for (int j = t; j < 4 * CC; j += 384) {
    int k = j / CC, c = j - k * CC;
    int ls = l - 3 + k;
    sseq[k][c] = (ls >= 0) ? seq[(tb * 32 + ls) * CC + c] : 0.f;
  }
  __syncthreads();
  int wid = t >> 6, lane = t & 63;
  if (wid < 4) {
    float sm = 0.f, sq = 0.f;
    for (int e = lane; e < CC; e += 64) { float v = sseq[wid][e]; sm += v; sq += v * v; }
    #pragma unroll
    for (int off = 32; off > 0; off >>= 1) { sm += __shfl_down(sm, off, 64); sq += __shfl_down(sq, off, 64); }
    if (lane == 0) { float mu = sm / CC; smu[wid] = mu; sri[wid] = rsqrtf(sq / CC - mu * mu + 1e-5f); }
  }
  __syncthreads();
  for (int j = t; j < 4 * CC; j += 384) {
    int k = j / CC, c = j - k * CC;
    sseq[k][c] = (sseq[k][c] - smu[k]) * sri[k] * ln_w[i * CC + c] + ln_b[i * CC + c];
  }
  __syncthreads();
  {
    const float4* wr = (const float4*)(in_w + ((size_t)i * 768 + t) * CC);
    const float4* wz = (const float4*)(in_w + ((size_t)i * 768 + 384 + t) * CC);
    const float4* s0 = (const float4*)sseq[0];
    const float4* s1 = (const float4*)sseq[1];
    const float4* s2 = (const float4*)sseq[2];
    const float4* s3 = (const float4*)sseq[3];
    float a0 = 0.f, a1 = 0.f, a2 = 0.f, a3 = 0.f, az = 0.f;
    #pragma unroll 4
    for (int c4 = 0; c4 < CC / 4; ++c4) {
      float4 w = wr[c4];
      float4 q0 = s0[c4], q1 = s1[c4], q2 = s2[c4], q3 = s3[c4];
      a0 += w.x * q0.x + w.y * q0.y + w.z * q0.z + w.w * q0.w;
      a1 += w.x * q1.x + w.y * q1.y + w.z * q1.z + w.w * q1.w;
      a2 += w.x * q2.x + w.y * q2.y + w.z * q2.z + w.w * q2.w;
      a3 += w.x * q3.x + w.y * q3.y + w.z * q3.z + w.w * q3.w;
      float4 z = wz[c4];
      az += z.x * q3.x + z.y * q3.y + z.z * q3.z + z.w * q3.w;
    }
    int bl = l - 3;
    sxm[0][t] = (bl + 0 >= 0) ? a0 : 0.f;
    sxm[1][t] = (bl + 1 >= 0) ? a1 : 0.f;
    sxm[2][t] = (bl + 2 >= 0) ? a2 : 0.f;
    sxm[3][t] = a3;
    zbuf[(size_t)tok * DI + t] = az;
  }
  __syncthreads();
  {
    int di = t;
    const float* cw = conv_w + ((size_t)i * DI + di) * KK;
    float acc = conv_b[i * DI + di];
    #pragma unroll
    for (int k = 0; k < KK; ++k) acc += cw[k] * sxm[k][di];
    acc = acc / (1.f + expf(-acc));
    xcl[di] = acc;
    xc[(size_t)tok * DI + di] = acc;
  }
  __syncthreads();
  if (t < 352) {
    int o = t >> 3, ln8 = t & 7;
    const float4* wr = (const float4*)(xp_w + ((size_t)i * 44 + o) * DI);
    const float4* xv = (const float4*)xcl;
    float acc = 0.f;
    #pragma unroll
    for (int c4 = ln8 * 12; c4 < ln8 * 12 + 12; ++c4) {
      float4 a = wr[c4], bq = xv[c4];
      acc += a.x * bq.x + a.y * bq.y + a.z * bq.z + a.w * bq.w;
    }
    #pragma unroll
    for (int off = 4; off > 0; off >>= 1) acc += __shfl_xor(acc, off, 8);
    if (ln8 == 0) { dbcl[o] = acc; dbc[tok * 44 + o] = acc; }
  }
  __syncthreads();
  {
    int di = t;
    const float* wr = dt_w + ((size_t)i * DI + di) * RR;
    float acc = dt_b[i * DI + di];
    #pragma unroll
    for (int r = 0; r < RR; ++r) acc += wr[r] * dbcl[r];
    float sp = (acc > 20.f) ? acc : log1pf(expf(acc));
    dtout[(size_t)tok * DI + di] = sp;
  }
}

// ---------------- K3: scan, shuffle-free serial loop; LDS partials + cooperative reduce ----------------
// grid = 288 (6 ib x 48 chunks), block = 128 (8 di x 16 s)
__global__ void k_scan(const float* __restrict__ dbc, const float* __restrict__ dtin,
                       const float* __restrict__ xc, const float* __restrict__ zbuf,
                       const float* __restrict__ A_log, const float* __restrict__ Dskip,
                       float* __restrict__ y, float* __restrict__ ymean) {
  int ib = blockIdx.x / 48;
  int di0 = (blockIdx.x % 48) * 8;
  int i = ib / BB;
  int t = threadIdx.x;
  int g = t >> 4, s = t & 15;
  int di = di0 + g;
  __shared__ float sdt[32][8], sxc[32][8], sz[32][8];
  __shared__ float sB[32][SS], sC[32][SS];
  __shared__ float spp[32 * 136];
  __shared__ float sy[32][8];
  __shared__ float sDsk[8];
  #pragma unroll
  for (int j = t; j < 256; j += 128) {
    int l = j >> 3, gg = j & 7;
    int tok = ib * 32 + l;
    sdt[l][gg] = dtin[(size_t)tok * DI + di0 + gg];
    sxc[l][gg] = xc[(size_t)tok * DI + di0 + gg];
    sz[l][gg]  = zbuf[(size_t)tok * DI + di0 + gg];
  }
  #pragma unroll
  for (int j = t; j < 512; j += 128) {
    int l = j >> 4, ss = j & 15;
    sB[l][ss] = dbc[(ib * 32 + l) * 44 + RR + ss];
    sC[l][ss] = dbc[(ib * 32 + l) * 44 + RR + SS + ss];
  }
  if (t < 8) sDsk[t] = Dskip[i * DI + di0 + t];
  float A = -expf(A_log[((size_t)i * DI + di) * SS + s]);
  float h = 0.f;
  __syncthreads();
  #pragma unroll
  for (int l = 0; l < 32; ++l) {
    float dtt = sdt[l][g];
    h = expf(dtt * A) * h + dtt * sxc[l][g] * sB[l][s];
    spp[l * 136 + g * 17 + s] = h * sC[l][s];
  }
  __syncthreads();
  #pragma unroll
  for (int p = 0; p < 2; ++p) {
    int idx = p * 128 + t;
    int l = idx >> 3, g2 = idx & 7;
    float sum = 0.f;
    #pragma unroll
    for (int s2 = 0; s2 < 16; ++s2) sum += spp[l * 136 + g2 * 17 + s2];
    float xt = sxc[l][g2];
    float z  = sz[l][g2];
    float yv = (sum + sDsk[g2] * xt) * (z / (1.f + expf(-z)));
    y[(size_t)(ib * 32 + l) * DI + di0 + g2] = yv;
    sy[l][g2] = yv;
  }
  __syncthreads();
  if (t < 8) {
    float sum = 0.f;
    #pragma unroll
    for (int l = 0; l < 32; ++l) sum += sy[l][t];
    ymean[ib * DI + di0 + t] = sum * (1.f / 32.f);
  }
}

// ---------------- K4: ctx precompute: Zmean (analytic, via ymean) -> Wg -> ctx ----------------
// grid = 6 (g*B+b), block = 384
__global__ void k_ctx(const float* __restrict__ ymean, const float* __restrict__ out_w,
                      const float* __restrict__ up_w, const float* __restrict__ up_b,
                      const float* __restrict__ Wg_w, const float* __restrict__ Wg_b,
                      float* __restrict__ ctx) {
  int blk = blockIdx.x; int g = blk / BB, b = blk - g * BB;
  int o1 = (g == 0) ? 1 : 0, o2 = (g == 2) ? 1 : 2;
  int t = threadIdx.x;
  int o = (t < 192) ? t : t - 192;
  int ph = (t < 192) ? 0 : 1;
  __shared__ float ym1[DI], ym2[DI];
  __shared__ float m1[CC], m2[CC], zm1[CC], zm2[CC];
  __shared__ float pa[384], pb[384];
  ym1[t] = ymean[(o1 * BB + b) * DI + t];
  ym2[t] = ymean[(o2 * BB + b) * DI + t];
  __syncthreads();
  {
    const float4* wa = (const float4*)(out_w + ((size_t)o1 * CC + o) * DI);
    const float4* wb = (const float4*)(out_w + ((size_t)o2 * CC + o) * DI);
    const float4* v1 = (const float4*)ym1;
    const float4* v2 = (const float4*)ym2;
    float a1 = 0.f, a2 = 0.f;
    #pragma unroll 4
    for (int c4 = ph * 48; c4 < ph * 48 + 48; ++c4) {
      float4 wA = wa[c4], qA = v1[c4];
      a1 += wA.x * qA.x + wA.y * qA.y + wA.z * qA.z + wA.w * qA.w;
      float4 wB = wb[c4], qB = v2[c4];
      a2 += wB.x * qB.x + wB.y * qB.y + wB.z * qB.z + wB.w * qB.w;
    }
    pa[t] = a1; pb[t] = a2;
  }
  __syncthreads();
  if (t < 192) { m1[t] = pa[t] + pa[t + 192]; m2[t] = pb[t] + pb[t + 192]; }
  __syncthreads();
  {
    const float4* ua = (const float4*)(up_w + ((size_t)o1 * CC + o) * CC);
    const float4* ub = (const float4*)(up_w + ((size_t)o2 * CC + o) * CC);
    const float4* v1 = (const float4*)m1;
    const float4* v2 = (const float4*)m2;
    float a1 = 0.f, a2 = 0.f;
    #pragma unroll 4
    for (int c4 = ph * 24; c4 < ph * 24 + 24; ++c4) {
      float4 wA = ua[c4], qA = v1[c4];
      a1 += wA.x * qA.x + wA.y * qA.y + wA.z * qA.z + wA.w * qA.w;
      float4 wB = ub[c4], qB = v2[c4];
      a2 += wB.x * qB.x + wB.y * qB.y + wB.z * qB.z + wB.w * qB.w;
    }
    pa[t] = a1; pb[t] = a2;
  }
  __syncthreads();
  if (t < 192) {
    zm1[t] = up_b[o1 * CC + t] + pa[t] + pa[t + 192];
    zm2[t] = up_b[o2 * CC + t] + pb[t] + pb[t + 192];
  }
  __syncthreads();
  {
    const float4* gwr = (const float4*)(Wg_w + (size_t)o * 2 * CC + ph * CC);
    const float4* gmv = (const float4*)(ph == 0 ? zm1 : zm2);
    float acc = 0.f;
    #pragma unroll 4
    for (int c4 = 0; c4 < 48; ++c4) {
      float4 a = gwr[c4], bq = gmv[c4];
      acc += a.x * bq.x + a.y * bq.y + a.z * bq.z + a.w * bq.w;
    }
    pa[t] = acc;
  }
  __syncthreads();
  if (t < 192) ctx[blk * CC + t] = Wg_b[t] + pa[t] + pa[t + 192];
}

// ---------------- K5: gate per token: out_w -> up_w -> Ws -> relu(ctx+st) -> Wm -> po ----------------
// grid = 192, block = 384
__global__ void k_gate(const float* __restrict__ y, const float* __restrict__ ctx,
                       const float* __restrict__ out_w, const float* __restrict__ up_w,
                       const float* __restrict__ up_b, const float* __restrict__ Ws_w,
                       const float* __restrict__ Ws_b, const float* __restrict__ Wm_w,
                       const float* __restrict__ Wm_b, const float* __restrict__ po_w,
                       float* __restrict__ P) {
  int blk = blockIdx.x; int gb = blk >> 5; int g = gb / BB;
  int t = threadIdx.x;
  __shared__ float yrow[DI];
  __shared__ float mrow[CC], zrow[CC], arow[CC], ygr[CC];
  __shared__ float pa[384];
  yrow[t] = y[(size_t)blk * DI + t];
  __syncthreads();
  int o = (t < 192) ? t : t - 192;
  int ph = (t < 192) ? 0 : 1;
  {
    const float4* wg = (const float4*)(out_w + ((size_t)g * CC + o) * DI);
    const float4* yv = (const float4*)yrow;
    float a0 = 0.f;
    #pragma unroll 4
    for (int c4 = ph * 48; c4 < ph * 48 + 48; ++c4) {
      float4 w0 = wg[c4], q0 = yv[c4];
      a0 += w0.x * q0.x + w0.y * q0.y + w0.z * q0.z + w0.w * q0.w;
    }
    pa[t] = a0;
  }
  __syncthreads();
  if (t < 192) mrow[t] = pa[t] + pa[t + 192];
  __syncthreads();
  {
    const float4* ug = (const float4*)(up_w + ((size_t)g * CC + o) * CC);
    const float4* mv = (const float4*)mrow;
    float a0 = 0.f;
    #pragma unroll 4
    for (int c4 = ph * 24; c4 < ph * 24 + 24; ++c4) {
      float4 w0 = ug[c4], q0 = mv[c4];
      a0 += w0.x * q0.x + w0.y * q0.y + w0.z * q0.z + w0.w * q0.w;
    }
    pa[t] = a0;
  }
  __syncthreads();
  if (t < 192) zrow[t] = up_b[g * CC + t] + pa[t] + pa[t + 192];
  __syncthreads();
  {
    const float4* wr = (const float4*)(Ws_w + (size_t)o * CC);
    const float4* zv = (const float4*)zrow;
    float acc = 0.f;
    #pragma unroll 4
    for (int c4 = ph * 24; c4 < ph * 24 + 24; ++c4) {
      float4 a = wr[c4], bq = zv[c4];
      acc += a.x * bq.x + a.y * bq.y + a.z * bq.z + a.w * bq.w;
    }
    pa[t] = acc;
  }
  __syncthreads();
  if (t < 192) {
    float a = ctx[gb * CC + t] + Ws_b[t] + pa[t] + pa[t + 192];
    arow[t] = a > 0.f ? a : 0.f;
  }
  __syncthreads();
  {
    const float4* mr = (const float4*)(Wm_w + (size_t)o * CC);
    const float4* av = (const float4*)arow;
    float acc = 0.f;
    #pragma unroll 4
    for (int c4 = ph * 24; c4 < ph * 24 + 24; ++c4) {
      float4 a = mr[c4], bq = av[c4];
      acc += a.x * bq.x + a.y * bq.y + a.z * bq.z + a.w * bq.w;
    }
    pa[t] = acc;
  }
  __syncthreads();
  if (t < 192) {
    float am = Wm_b[t] + pa[t] + pa[t + 192];
    am = 1.f / (1.f + expf(-am));
    ygr[t] = am * zrow[t];
  }
  __syncthreads();
  {
    const float4* pr = (const float4*)(po_w + (size_t)o * (3 * CC) + g * CC);
    const float4* yv = (const float4*)ygr;
    float acc = 0.f;
    #pragma unroll 4
    for (int c4 = ph * 24; c4 < ph * 24 + 24; ++c4) {
      float4 a = pr[c4], bq = yv[c4];
      acc += a.x * bq.x + a.y * bq.y + a.z * bq.z + a.w * bq.w;
    }
    pa[t] = acc;
  }
  __syncthreads();
  if (t < 192) P[(size_t)blk * CC + t] = pa[t] + pa[t + 192];
}

// ---------------- K6: final: warp-parallel separable stats + broadcast + residual ----------------
// grid = B*C*2, block = 256
__global__ void k_final(const float* __restrict__ x, const float* __restrict__ P,
                        const float* __restrict__ po_b, const float* __restrict__ rs_p,
                        float* __restrict__ out) {
  int bc = blockIdx.x >> 1; int half = blockIdx.x & 1;
  int b = bc / CC, c = bc % CC;
  __shared__ float p0[32], p1[32], p2[32];
  __shared__ float sbase;
  int t = threadIdx.x;
  if (t < 32) {
    float v0 = P[((0 * BB + b) * 32 + t) * CC + c];
    float v1 = P[((1 * BB + b) * 32 + t) * CC + c];
    float v2 = P[((2 * BB + b) * 32 + t) * CC + c];
    float s0 = v0, q0 = v0 * v0, s1 = v1, q1 = v1 * v1, s2 = v2, q2 = v2 * v2;
    #pragma unroll
    for (int off = 16; off > 0; off >>= 1) {
      s0 += __shfl_xor(s0, off, 32); q0 += __shfl_xor(q0, off, 32);
      s1 += __shfl_xor(s1, off, 32); q1 += __shfl_xor(q1, off, 32);
      s2 += __shfl_xor(s2, off, 32); q2 += __shfl_xor(q2, off, 32);
    }
    float m0 = s0 * (1.f / 32.f), m1 = s1 * (1.f / 32.f), m2 = s2 * (1.f / 32.f);
    float var = (q0 * (1.f / 32.f) - m0 * m0) + (q1 * (1.f / 32.f) - m1 * m1) + (q2 * (1.f / 32.f) - m2 * m2);
    float mu = po_b[c] + m0 + m1 + m2;
    float sc = rs_p[0] * rsqrtf(var + 1e-5f);
    p0[t] = v0 * sc; p1[t] = v1 * sc; p2[t] = v2 * sc;
    if (t == 0) sbase = sc * (po_b[c] - mu);
  }
  __syncthreads();
  float basev = sbase;
  const float4* xin = (const float4*)(x + (size_t)bc * 32768);
  float4* xo = (float4*)(out + (size_t)bc * 32768);
  int q0i = half * 4096;
  #pragma unroll 4
  for (int q = q0i + t; q < q0i + 4096; q += 256) {
    int d = q >> 8, h = (q >> 3) & 31, w4 = (q & 7) * 4;
    float add = basev + p0[d] + p1[h];
    float4 v = xin[q];
    v.x += add + p2[w4];
    v.y += add + p2[w4 + 1];
    v.z += add + p2[w4 + 2];
    v.w += add + p2[w4 + 3];
    xo[q] = v;
  }
}

extern "C" void kernel_launch(void* const* d_in, const int* in_sizes, int n_in,
                              void* d_out, int out_size, void* d_ws, size_t ws_size,
                              hipStream_t stream) {
  const float* x      = (const float*)d_in[0];
  const float* ln_w   = (const float*)d_in[1];
  const float* ln_b   = (const float*)d_in[2];
  const float* in_w   = (const float*)d_in[3];
  const float* conv_w = (const float*)d_in[4];
  const float* conv_b = (const float*)d_in[5];
  const float* xp_w   = (const float*)d_in[6];
  const float* dt_w   = (const float*)d_in[7];
  const float* dt_b   = (const float*)d_in[8];
  const float* A_log  = (const float*)d_in[9];
  const float* Dskip  = (const float*)d_in[10];
  const float* out_w  = (const float*)d_in[11];
  const float* up_w   = (const float*)d_in[12];
  const float* up_b   = (const float*)d_in[13];
  const float* Wg_w   = (const float*)d_in[14];
  const float* Wg_b   = (const float*)d_in[15];
  const float* Ws_w   = (const float*)d_in[16];
  const float* Ws_b   = (const float*)d_in[17];
  const float* Wm_w   = (const float*)d_in[18];
  const float* Wm_b   = (const float*)d_in[19];
  const float* po_w   = (const float*)d_in[20];
  const float* po_b   = (const float*)d_in[21];
  const float* rs_p   = (const float*)d_in[22];
  float* out = (float*)d_out;

  float* ws    = (float*)d_ws;
  float* seq   = ws;                 // 36864
  float* xc    = seq   + 36864;      // 73728
  float* zbuf  = xc    + 73728;      // 73728
  float* dbc   = zbuf  + 73728;      // 8448
  float* dt    = dbc   + 8448;       // 73728
  float* y     = dt    + 73728;      // 73728
  float* ymean = y     + 73728;      // 2304
  float* ctxb  = ymean + 2304;       // 1152
  float* P     = ctxb  + 1152;       // 36864

  k_reduce <<<dim3(BB * CC),     dim3(1024), 0, stream>>>(x, seq);
  k_convall<<<dim3(3 * BB * 32), dim3(384),  0, stream>>>(seq, ln_w, ln_b, in_w, conv_w, conv_b,
                                                          xp_w, dt_w, dt_b, xc, zbuf, dbc, dt);
  k_scan   <<<dim3(288),         dim3(128),  0, stream>>>(dbc, dt, xc, zbuf, A_log, Dskip, y, ymean);
  k_ctx    <<<dim3(6),           dim3(384),  0, stream>>>(ymean, out_w, up_w, up_b, Wg_w, Wg_b, ctxb);
  k_gate   <<<dim3(3 * BB * 32), dim3(384),  0, stream>>>(y, ctxb, out_w, up_w, up_b, Ws_w, Ws_b,
                                                          Wm_w, Wm_b, po_w, P);
  k_final  <<<dim3(BB * CC * 2), dim3(256),  0, stream>>>(x, P, po_b, rs_p, out);
}

// Round 6
// 114.745 us; speedup vs baseline: 1.2307x; 1.2307x over previous
//
#include <hip/hip_runtime.h>
#include <math.h>

#define BB 2
#define CC 192
#define DI 384
#define SS 16
#define RR 12
#define KK 4

// ---------------- K1: one pass over x, all three axis-mean reductions ----------------
// grid = B*C, block = 1024. seq layout: seq[i][b][pos][c]
__global__ void k_reduce(const float* __restrict__ x, float* __restrict__ seq) {
  int bc = blockIdx.x; int b = bc / CC, c = bc % CC;
  const float* base = x + (size_t)bc * 32768;
  int t = threadIdx.x;
  int w = t & 31, r = t >> 5;
  float acc = 0.f;
  __shared__ float sH[32];
  __shared__ float sMat[1024];
  if (t < 32) sH[t] = 0.f;
  __syncthreads();
  for (int h = 0; h < 32; ++h) {
    float v = base[r * 1024 + h * 32 + w];
    acc += v;
    float vv = v;
    #pragma unroll
    for (int off = 32; off > 0; off >>= 1) vv += __shfl_down(vv, off, 64);
    if ((t & 63) == 0) atomicAdd(&sH[h], vv);
  }
  sMat[t] = acc;
  float s0 = acc;
  #pragma unroll
  for (int off = 16; off > 0; off >>= 1) s0 += __shfl_down(s0, off, 32);
  if (w == 0) seq[((0 * BB + b) * 32 + r) * CC + c] = s0 * (1.f / 1024.f);
  __syncthreads();
  if (t < 32) {
    float s2 = 0.f;
    for (int rr = 0; rr < 32; ++rr) s2 += sMat[rr * 32 + t];
    seq[((2 * BB + b) * 32 + t) * CC + c] = s2 * (1.f / 1024.f);
    seq[((1 * BB + b) * 32 + t) * CC + c] = sH[t] * (1.f / 1024.f);
  }
}

// ---------------- K2: LN (recomputed per block) + in-proj, wide ----------------
// grid = 192 tok * 3 chunks = 576, block = 256 (256 outputs per chunk)
__global__ void k_lninproj(const float* __restrict__ seq, const float* __restrict__ ln_w,
                           const float* __restrict__ ln_b, const float* __restrict__ in_w,
                           float* __restrict__ xmz) {
  int blk = blockIdx.x;
  int tok = blk / 3, chunk = blk - tok * 3;
  int i = tok >> 6;
  int t = threadIdx.x;
  __shared__ float srow[CC];
  __shared__ float sw[4], qw[4];
  float v = (t < CC) ? seq[tok * CC + t] : 0.f;
  float s = v, q = v * v;
  #pragma unroll
  for (int off = 32; off > 0; off >>= 1) { s += __shfl_down(s, off, 64); q += __shfl_down(q, off, 64); }
  if ((t & 63) == 0) { sw[t >> 6] = s; qw[t >> 6] = q; }
  __syncthreads();
  float S = sw[0] + sw[1] + sw[2] + sw[3];
  float Q = qw[0] + qw[1] + qw[2] + qw[3];
  float mu = S / CC;
  float var = Q / CC - mu * mu;
  if (t < CC) srow[t] = (v - mu) * rsqrtf(var + 1e-5f) * ln_w[i * CC + t] + ln_b[i * CC + t];
  __syncthreads();
  int j = chunk * 256 + t;   // 0..767
  const float4* wr = (const float4*)(in_w + ((size_t)i * 768 + j) * CC);
  const float4* sr = (const float4*)srow;
  float acc = 0.f;
  #pragma unroll 8
  for (int c4 = 0; c4 < CC / 4; ++c4) {
    float4 a = wr[c4], bq = sr[c4];
    acc += a.x * bq.x + a.y * bq.y + a.z * bq.z + a.w * bq.w;
  }
  xmz[(size_t)tok * 768 + j] = acc;
}

// ---------------- K3: conv+silu + xp-proj + dt-proj+softplus, per token ----------------
// grid = 192, block = 384
__global__ void k_convxpdt(const float* __restrict__ xmz, const float* __restrict__ conv_w,
                           const float* __restrict__ conv_b, const float* __restrict__ xp_w,
                           const float* __restrict__ dt_w, const float* __restrict__ dt_b,
                           float* __restrict__ xc, float* __restrict__ dbc,
                           float* __restrict__ dtout) {
  int tok = blockIdx.x; int l = tok & 31; int tb = tok >> 5; int i = tb / BB;
  int t = threadIdx.x;
  __shared__ float xcl[DI];
  __shared__ float dbcl[44];
  {
    int di = t;
    const float* cw = conv_w + ((size_t)i * DI + di) * KK;
    float acc = conv_b[i * DI + di];
    #pragma unroll
    for (int k = 0; k < KK; ++k) {
      int ls = l + k - 3;
      if (ls >= 0) acc += cw[k] * xmz[(size_t)(tb * 32 + ls) * 768 + di];
    }
    acc = acc / (1.f + expf(-acc));
    xcl[di] = acc;
    xc[(size_t)tok * DI + di] = acc;
  }
  __syncthreads();
  if (t < 352) {
    int o = t >> 3, ln8 = t & 7;
    const float4* wr = (const float4*)(xp_w + ((size_t)i * 44 + o) * DI);
    const float4* xv = (const float4*)xcl;
    float acc = 0.f;
    #pragma unroll
    for (int c4 = ln8 * 12; c4 < ln8 * 12 + 12; ++c4) {
      float4 a = wr[c4], bq = xv[c4];
      acc += a.x * bq.x + a.y * bq.y + a.z * bq.z + a.w * bq.w;
    }
    #pragma unroll
    for (int off = 4; off > 0; off >>= 1) acc += __shfl_xor(acc, off, 8);
    if (ln8 == 0) { dbcl[o] = acc; dbc[tok * 44 + o] = acc; }
  }
  __syncthreads();
  {
    int di = t;
    const float* wr = dt_w + ((size_t)i * DI + di) * RR;
    float acc = dt_b[i * DI + di];
    #pragma unroll
    for (int r = 0; r < RR; ++r) acc += wr[r] * dbcl[r];
    float sp = (acc > 20.f) ? acc : log1pf(expf(acc));
    dtout[(size_t)tok * DI + di] = sp;
  }
}

// ---------------- K4: scan, shuffle-free serial loop; z read from xmz ----------------
// grid = 288 (6 ib x 48 chunks), block = 128 (8 di x 16 s)
__global__ void k_scan(const float* __restrict__ dbc, const float* __restrict__ dtin,
                       const float* __restrict__ xc, const float* __restrict__ xmz,
                       const float* __restrict__ A_log, const float* __restrict__ Dskip,
                       float* __restrict__ y, float* __restrict__ ymean) {
  int ib = blockIdx.x / 48;
  int di0 = (blockIdx.x % 48) * 8;
  int i = ib / BB;
  int t = threadIdx.x;
  int g = t >> 4, s = t & 15;
  int di = di0 + g;
  __shared__ float sdt[32][8], sxc[32][8], sz[32][8];
  __shared__ float sB[32][SS], sC[32][SS];
  __shared__ float spp[32 * 136];
  __shared__ float sy[32][8];
  __shared__ float sDsk[8];
  #pragma unroll
  for (int j = t; j < 256; j += 128) {
    int l = j >> 3, gg = j & 7;
    int tok = ib * 32 + l;
    sdt[l][gg] = dtin[(size_t)tok * DI + di0 + gg];
    sxc[l][gg] = xc[(size_t)tok * DI + di0 + gg];
    sz[l][gg]  = xmz[(size_t)tok * 768 + DI + di0 + gg];
  }
  #pragma unroll
  for (int j = t; j < 512; j += 128) {
    int l = j >> 4, ss = j & 15;
    sB[l][ss] = dbc[(ib * 32 + l) * 44 + RR + ss];
    sC[l][ss] = dbc[(ib * 32 + l) * 44 + RR + SS + ss];
  }
  if (t < 8) sDsk[t] = Dskip[i * DI + di0 + t];
  float A = -expf(A_log[((size_t)i * DI + di) * SS + s]);
  float h = 0.f;
  __syncthreads();
  #pragma unroll
  for (int l = 0; l < 32; ++l) {
    float dtt = sdt[l][g];
    h = expf(dtt * A) * h + dtt * sxc[l][g] * sB[l][s];
    spp[l * 136 + g * 17 + s] = h * sC[l][s];
  }
  __syncthreads();
  #pragma unroll
  for (int p = 0; p < 2; ++p) {
    int idx = p * 128 + t;
    int l = idx >> 3, g2 = idx & 7;
    float sum = 0.f;
    #pragma unroll
    for (int s2 = 0; s2 < 16; ++s2) sum += spp[l * 136 + g2 * 17 + s2];
    float xt = sxc[l][g2];
    float z  = sz[l][g2];
    float yv = (sum + sDsk[g2] * xt) * (z / (1.f + expf(-z)));
    y[(size_t)(ib * 32 + l) * DI + di0 + g2] = yv;
    sy[l][g2] = yv;
  }
  __syncthreads();
  if (t < 8) {
    float sum = 0.f;
    #pragma unroll
    for (int l = 0; l < 32; ++l) sum += sy[l][t];
    ymean[ib * DI + di0 + t] = sum * (1.f / 32.f);
  }
}

// ---------------- K5: mrow = out_w @ {y[tok] | ymean[ib]} ; 198 jobs ----------------
// grid = 198, block = 384 (2 threads per output row)
__global__ void k_mrow(const float* __restrict__ y, const float* __restrict__ ymean,
                       const float* __restrict__ out_w, float* __restrict__ mrow) {
  int j = blockIdx.x;
  int t = threadIdx.x;
  __shared__ float src[DI];
  __shared__ float pa[384];
  int i;
  if (j < 192) { i = j >> 6; src[t] = y[(size_t)j * DI + t]; }
  else         { i = (j - 192) / BB; src[t] = ymean[(j - 192) * DI + t]; }
  __syncthreads();
  int o = (t < 192) ? t : t - 192;
  int ph = (t < 192) ? 0 : 1;
  const float4* wr = (const float4*)(out_w + ((size_t)i * CC + o) * DI);
  const float4* sv = (const float4*)src;
  float acc = 0.f;
  #pragma unroll 8
  for (int c4 = ph * 48; c4 < ph * 48 + 48; ++c4) {
    float4 a = wr[c4], bq = sv[c4];
    acc += a.x * bq.x + a.y * bq.y + a.z * bq.z + a.w * bq.w;
  }
  pa[t] = acc;
  __syncthreads();
  if (t < 192) mrow[(size_t)j * CC + t] = pa[t] + pa[t + 192];
}

// ---------------- K6: zrow = up_b + up_w @ mrow ; 198 jobs ----------------
// grid = 198, block = 384
__global__ void k_zrow(const float* __restrict__ mrow, const float* __restrict__ up_w,
                       const float* __restrict__ up_b, float* __restrict__ zrow) {
  int j = blockIdx.x;
  int t = threadIdx.x;
  __shared__ float src[CC];
  __shared__ float pa[384];
  int i = (j < 192) ? (j >> 6) : (j - 192) / BB;
  if (t < CC) src[t] = mrow[(size_t)j * CC + t];
  __syncthreads();
  int o = (t < 192) ? t : t - 192;
  int ph = (t < 192) ? 0 : 1;
  const float4* ur = (const float4*)(up_w + ((size_t)i * CC + o) * CC);
  const float4* sv = (const float4*)src;
  float acc = 0.f;
  #pragma unroll 8
  for (int c4 = ph * 24; c4 < ph * 24 + 24; ++c4) {
    float4 a = ur[c4], bq = sv[c4];
    acc += a.x * bq.x + a.y * bq.y + a.z * bq.z + a.w * bq.w;
  }
  pa[t] = acc;
  __syncthreads();
  if (t < 192) zrow[(size_t)j * CC + t] = up_b[i * CC + t] + pa[t] + pa[t + 192];
}

// ---------------- K7: gate per token: (Ws@z || Wg@zm) -> relu -> Wm -> sigmoid -> po ----------------
// grid = 192, block = 384
__global__ void k_gate(const float* __restrict__ zrow, const float* __restrict__ Wg_w,
                       const float* __restrict__ Wg_b, const float* __restrict__ Ws_w,
                       const float* __restrict__ Ws_b, const float* __restrict__ Wm_w,
                       const float* __restrict__ Wm_b, const float* __restrict__ po_w,
                       float* __restrict__ P) {
  int blk = blockIdx.x; int gb = blk >> 5; int g = gb / BB, b = gb - g * BB;
  int o1 = (g == 0) ? 1 : 0, o2 = (g == 2) ? 1 : 2;
  int t = threadIdx.x;
  __shared__ float zr[CC], zm[2][CC], arow[CC], ygr[CC];
  __shared__ float pa[384], pb[384];
  if (t < CC) {
    zr[t] = zrow[(size_t)blk * CC + t];
    zm[0][t] = zrow[(size_t)(192 + o1 * BB + b) * CC + t];
  } else {
    int tt = t - CC;
    zm[1][tt] = zrow[(size_t)(192 + o2 * BB + b) * CC + tt];
  }
  __syncthreads();
  int o = (t < 192) ? t : t - 192;
  int ph = (t < 192) ? 0 : 1;
  { // Ws half-dot + Wg full-dot (ph selects which zm/Wg half)
    const float4* wr = (const float4*)(Ws_w + (size_t)o * CC);
    const float4* zv = (const float4*)zr;
    float acc = 0.f;
    #pragma unroll 4
    for (int c4 = ph * 24; c4 < ph * 24 + 24; ++c4) {
      float4 a = wr[c4], bq = zv[c4];
      acc += a.x * bq.x + a.y * bq.y + a.z * bq.z + a.w * bq.w;
    }
    pa[t] = acc;
    const float4* gwr = (const float4*)(Wg_w + (size_t)o * 2 * CC + ph * CC);
    const float4* gmv = (const float4*)zm[ph];
    float acc2 = 0.f;
    #pragma unroll 4
    for (int c4 = 0; c4 < 48; ++c4) {
      float4 a = gwr[c4], bq = gmv[c4];
      acc2 += a.x * bq.x + a.y * bq.y + a.z * bq.z + a.w * bq.w;
    }
    pb[t] = acc2;
  }
  __syncthreads();
  if (t < 192) {
    float a = (Ws_b[t] + pa[t] + pa[t + 192]) + (Wg_b[t] + pb[t] + pb[t + 192]);
    arow[t] = a > 0.f ? a : 0.f;
  }
  __syncthreads();
  {
    const float4* mr = (const float4*)(Wm_w + (size_t)o * CC);
    const float4* av = (const float4*)arow;
    float acc = 0.f;
    #pragma unroll 4
    for (int c4 = ph * 24; c4 < ph * 24 + 24; ++c4) {
      float4 a = mr[c4], bq = av[c4];
      acc += a.x * bq.x + a.y * bq.y + a.z * bq.z + a.w * bq.w;
    }
    pa[t] = acc;
  }
  __syncthreads();
  if (t < 192) {
    float am = Wm_b[t] + pa[t] + pa[t + 192];
    am = 1.f / (1.f + expf(-am));
    ygr[t] = am * zr[t];
  }
  __syncthreads();
  {
    const float4* pr = (const float4*)(po_w + (size_t)o * (3 * CC) + g * CC);
    const float4* yv = (const float4*)ygr;
    float acc = 0.f;
    #pragma unroll 4
    for (int c4 = ph * 24; c4 < ph * 24 + 24; ++c4) {
      float4 a = pr[c4], bq = yv[c4];
      acc += a.x * bq.x + a.y * bq.y + a.z * bq.z + a.w * bq.w;
    }
    pb[t] = acc;
  }
  __syncthreads();
  if (t < 192) P[(size_t)blk * CC + t] = pb[t] + pb[t + 192];
}

// ---------------- K8: final: warp-parallel separable stats + broadcast + residual ----------------
// grid = B*C*2, block = 256
__global__ void k_final(const float* __restrict__ x, const float* __restrict__ P,
                        const float* __restrict__ po_b, const float* __restrict__ rs_p,
                        float* __restrict__ out) {
  int bc = blockIdx.x >> 1; int half = blockIdx.x & 1;
  int b = bc / CC, c = bc % CC;
  __shared__ float p0[32], p1[32], p2[32];
  __shared__ float sbase;
  int t = threadIdx.x;
  if (t < 32) {
    float v0 = P[((0 * BB + b) * 32 + t) * CC + c];
    float v1 = P[((1 * BB + b) * 32 + t) * CC + c];
    float v2 = P[((2 * BB + b) * 32 + t) * CC + c];
    float s0 = v0, q0 = v0 * v0, s1 = v1, q1 = v1 * v1, s2 = v2, q2 = v2 * v2;
    #pragma unroll
    for (int off = 16; off > 0; off >>= 1) {
      s0 += __shfl_xor(s0, off, 32); q0 += __shfl_xor(q0, off, 32);
      s1 += __shfl_xor(s1, off, 32); q1 += __shfl_xor(q1, off, 32);
      s2 += __shfl_xor(s2, off, 32); q2 += __shfl_xor(q2, off, 32);
    }
    float m0 = s0 * (1.f / 32.f), m1 = s1 * (1.f / 32.f), m2 = s2 * (1.f / 32.f);
    float var = (q0 * (1.f / 32.f) - m0 * m0) + (q1 * (1.f / 32.f) - m1 * m1) + (q2 * (1.f / 32.f) - m2 * m2);
    float mu = po_b[c] + m0 + m1 + m2;
    float sc = rs_p[0] * rsqrtf(var + 1e-5f);
    p0[t] = v0 * sc; p1[t] = v1 * sc; p2[t] = v2 * sc;
    if (t == 0) sbase = sc * (po_b[c] - mu);
  }
  __syncthreads();
  float basev = sbase;
  const float4* xin = (const float4*)(x + (size_t)bc * 32768);
  float4* xo = (float4*)(out + (size_t)bc * 32768);
  int q0i = half * 4096;
  #pragma unroll 4
  for (int q = q0i + t; q < q0i + 4096; q += 256) {
    int d = q >> 8, h = (q >> 3) & 31, w4 = (q & 7) * 4;
    float add = basev + p0[d] + p1[h];
    float4 v = xin[q];
    v.x += add + p2[w4];
    v.y += add + p2[w4 + 1];
    v.z += add + p2[w4 + 2];
    v.w += add + p2[w4 + 3];
    xo[q] = v;
  }
}

extern "C" void kernel_launch(void* const* d_in, const int* in_sizes, int n_in,
                              void* d_out, int out_size, void* d_ws, size_t ws_size,
                              hipStream_t stream) {
  const float* x      = (const float*)d_in[0];
  const float* ln_w   = (const float*)d_in[1];
  const float* ln_b   = (const float*)d_in[2];
  const float* in_w   = (const float*)d_in[3];
  const float* conv_w = (const float*)d_in[4];
  const float* conv_b = (const float*)d_in[5];
  const float* xp_w   = (const float*)d_in[6];
  const float* dt_w   = (const float*)d_in[7];
  const float* dt_b   = (const float*)d_in[8];
  const float* A_log  = (const float*)d_in[9];
  const float* Dskip  = (const float*)d_in[10];
  const float* out_w  = (const float*)d_in[11];
  const float* up_w   = (const float*)d_in[12];
  const float* up_b   = (const float*)d_in[13];
  const float* Wg_w   = (const float*)d_in[14];
  const float* Wg_b   = (const float*)d_in[15];
  const float* Ws_w   = (const float*)d_in[16];
  const float* Ws_b   = (const float*)d_in[17];
  const float* Wm_w   = (const float*)d_in[18];
  const float* Wm_b   = (const float*)d_in[19];
  const float* po_w   = (const float*)d_in[20];
  const float* po_b   = (const float*)d_in[21];
  const float* rs_p   = (const float*)d_in[22];
  float* out = (float*)d_out;

  float* ws    = (float*)d_ws;
  float* seq   = ws;                 // 36864
  float* xmz   = seq   + 36864;      // 147456
  float* xc    = xmz   + 147456;     // 73728
  float* dbc   = xc    + 73728;      // 8448
  float* dt    = dbc   + 8448;       // 73728
  float* y     = dt    + 73728;      // 73728
  float* ymean = y     + 73728;      // 2304
  float* mrow  = ymean + 2304;       // 198*192 = 38016
  float* zrow  = mrow  + 38016;      // 38016
  float* P     = zrow  + 38016;      // 36864

  k_reduce  <<<dim3(BB * CC),     dim3(1024), 0, stream>>>(x, seq);
  k_lninproj<<<dim3(576),         dim3(256),  0, stream>>>(seq, ln_w, ln_b, in_w, xmz);
  k_convxpdt<<<dim3(192),         dim3(384),  0, stream>>>(xmz, conv_w, conv_b, xp_w, dt_w, dt_b,
                                                           xc, dbc, dt);
  k_scan    <<<dim3(288),         dim3(128),  0, stream>>>(dbc, dt, xc, xmz, A_log, Dskip, y, ymean);
  k_mrow    <<<dim3(198),         dim3(384),  0, stream>>>(y, ymean, out_w, mrow);
  k_zrow    <<<dim3(198),         dim3(384),  0, stream>>>(mrow, up_w, up_b, zrow);
  k_gate    <<<dim3(192),         dim3(384),  0, stream>>>(zrow, Wg_w, Wg_b, Ws_w, Ws_b,
                                                           Wm_w, Wm_b, po_w, P);
  k_final   <<<dim3(BB * CC * 2), dim3(256),  0, stream>>>(x, P, po_b, rs_p, out);
}